// Round 4
// baseline (65.704 us; speedup 1.0000x reference)
//
#include <hip/hip_runtime.h>
#include <math.h>

#define NQ 4
#define NL 6
#define BLOCK 256

typedef float v2 __attribute__((ext_vector_type(2)));

// R4: TWO LANES PER SAMPLE. Sample = gid>>1, lane parity p = tid&1.
// Qubit->bit map of basis index i (bit3..bit0 = qubit0..qubit3):
//   bit3 (qubit 0) = lane parity p      <- cross-lane via shfl_xor(.,1)
//   bit2 (qubit 1) = reg index bit1
//   bit1 (qubit 2) = reg index bit0
//   bit0 (qubit 3) = slot within float2
// Each lane holds 8 amps: 4x float2 re + 4x float2 im (16 VGPRs of state).
// This doubles resident waves (2 -> 4 per SIMD): the kernel was latency-
// bound, not issue-bound (two rounds of instruction-halving gave only ~15%
// each), so TLP is the remaining lever.
// R1: layers rolled 2x3 (I-cache fit). R2/R3: packed v_pk_fma_f32 state.
__global__ __launch_bounds__(BLOCK) void vqc_kernel(
    const float* __restrict__ inputs,   // [B, 4]
    const float* __restrict__ rot,      // [6, 4, 3]
    float* __restrict__ out,            // [B, 4]
    int batch)
{
    __shared__ float U[NL * NQ][8];  // u00r,u00i,u01r,u01i,u10r,u10i,u11r,u11i

    const int tid = threadIdx.x;
    if (tid < NL * NQ) {
        float phi = rot[tid * 3 + 0];
        float theta = rot[tid * 3 + 1];
        float omega = rot[tid * 3 + 2];
        float st, ct;
        __sincosf(0.5f * theta, &st, &ct);
        float a = 0.5f * (phi + omega);   // ep = exp(-i a) = ca - i sa
        float b = 0.5f * (phi - omega);   // em = exp(+i b) = cb + i sb
        float sa, ca, sb, cb;
        __sincosf(a, &sa, &ca);
        __sincosf(b, &sb, &cb);
        U[tid][0] = ca * ct;   // u00 = ep*ct
        U[tid][1] = -sa * ct;
        U[tid][2] = -cb * st;  // u01 = -em*st
        U[tid][3] = -sb * st;
        U[tid][4] = cb * st;   // u10 = conj(em)*st
        U[tid][5] = -sb * st;
        U[tid][6] = ca * ct;   // u11 = conj(ep)*ct
        U[tid][7] = sa * ct;
    }
    __syncthreads();

    const int gid = blockIdx.x * BLOCK + tid;
    const int b = gid >> 1;
    const int p = gid & 1;
    if (b >= batch) return;

    // ---- AngleEmbedding: product state (this lane's 8 amps) ----
    const float4 x = ((const float4*)inputs)[b];
    float c[NQ], s[NQ];
    __sincosf(0.5f * x.x, &s[0], &c[0]);
    __sincosf(0.5f * x.y, &s[1], &c[1]);
    __sincosf(0.5f * x.z, &s[2], &c[2]);
    __sincosf(0.5f * x.w, &s[3], &c[3]);

    v2 sr[4], si[4];
    {
        const float f0 = p ? s[0] : c[0];
#pragma unroll
        for (int k = 0; k < 4; ++k) {
#pragma unroll
            for (int slot = 0; slot < 2; ++slot) {
                const float mag = f0 * (((k >> 1) & 1) ? s[1] : c[1])
                                     * ((k & 1) ? s[2] : c[2])
                                     * (slot ? s[3] : c[3]);
                const int n = ((k >> 1) & 1) + (k & 1) + slot;   // excludes p
                // base = (-i)^n * mag ; lane1 multiplies by extra (-i):
                // (x+iy)(-i) = (y, -x)
                const float xr_ = (n == 0) ? mag : ((n == 2) ? -mag : 0.f);
                const float xi_ = (n == 1) ? -mag : ((n == 3) ? mag : 0.f);
                const float rr = p ? xi_ : xr_;
                const float ri = p ? -xr_ : xi_;
                if (slot == 0) { sr[k].x = rr; si[k].x = ri; }
                else           { sr[k].y = rr; si[k].y = ri; }
            }
        }
    }

    // ---- StronglyEntanglingLayers: 2 macro-iterations x 3 layers ----
#pragma unroll 1
    for (int half = 0; half < 2; ++half) {
        const int ubase = half * (3 * NQ);
#pragma unroll
        for (int li = 0; li < 3; ++li) {
            // ---- Rot on qubit 0 (lane bit): cross-lane pair ----
            {
                const float* u = U[ubase + li * NQ + 0];
                const float ar = p ? u[6] : u[0], ai = p ? u[7] : u[1];
                const float br = p ? u[4] : u[2], bi = p ? u[5] : u[3];
#pragma unroll
                for (int k = 0; k < 4; ++k) {
                    const v2 xr = sr[k], xi = si[k];
                    v2 yr, yi;
                    yr.x = __shfl_xor(xr.x, 1); yr.y = __shfl_xor(xr.y, 1);
                    yi.x = __shfl_xor(xi.x, 1); yi.y = __shfl_xor(xi.y, 1);
                    sr[k] = ar * xr - ai * xi + br * yr - bi * yi;
                    si[k] = ar * xi + ai * xr + br * yi + bi * yr;
                }
            }
            // ---- Rot on qubits 1,2 (reg bits): in-lane pairs ----
#pragma unroll
            for (int q = 1; q <= 2; ++q) {
                const float* u = U[ubase + li * NQ + q];
                const float u00r = u[0], u00i = u[1], u01r = u[2], u01i = u[3];
                const float u10r = u[4], u10i = u[5], u11r = u[6], u11i = u[7];
                const int m = (q == 1) ? 2 : 1;
#pragma unroll
                for (int k = 0; k < 4; ++k) {
                    if (!(k & m)) {
                        const int k2 = k | m;
                        const v2 a0r = sr[k], a0i = si[k];
                        const v2 a1r = sr[k2], a1i = si[k2];
                        sr[k]  = u00r * a0r - u00i * a0i + u01r * a1r - u01i * a1i;
                        si[k]  = u00r * a0i + u00i * a0r + u01r * a1i + u01i * a1r;
                        sr[k2] = u10r * a0r - u10i * a0i + u11r * a1r - u11i * a1i;
                        si[k2] = u10r * a0i + u10i * a0r + u11r * a1i + u11i * a1r;
                    }
                }
            }
            // ---- Rot on qubit 3 (slot bit) ----
            {
                const float* u = U[ubase + li * NQ + 3];
                const v2 dr = {u[0], u[6]}, di = {u[1], u[7]};
                const v2 er = {u[2], u[4]}, ei = {u[3], u[5]};
#pragma unroll
                for (int k = 0; k < 4; ++k) {
                    const v2 xr = sr[k], xi = si[k];
                    const v2 yr = __builtin_shufflevector(xr, xr, 1, 0);
                    const v2 yi = __builtin_shufflevector(xi, xi, 1, 0);
                    sr[k] = dr * xr - di * xi + er * yr - ei * yi;
                    si[k] = dr * xi + di * xr + er * yi + ei * yr;
                }
            }
            // ---- CNOT ring, r = li+1, applied q = 0,1,2,3 in order ----
            if (li == 0) {
                // (0,1): c=lane, t=reg bit1 -> lane1 swaps (0,2),(1,3)
                { v2 a=sr[0],b_=sr[2]; sr[0]=p?b_:a; sr[2]=p?a:b_;
                  v2 ai_=si[0],bi_=si[2]; si[0]=p?bi_:ai_; si[2]=p?ai_:bi_;
                  v2 c_=sr[1],d_=sr[3]; sr[1]=p?d_:c_; sr[3]=p?c_:d_;
                  v2 ci_=si[1],di_=si[3]; si[1]=p?di_:ci_; si[3]=p?ci_:di_; }
                // (1,2): in-lane rename: swap regs 2,3
                { v2 t=sr[2]; sr[2]=sr[3]; sr[3]=t; t=si[2]; si[2]=si[3]; si[3]=t; }
                // (2,3): c=reg bit0, t=slot -> slot-swap regs 1,3
                sr[1]=__builtin_shufflevector(sr[1],sr[1],1,0);
                si[1]=__builtin_shufflevector(si[1],si[1],1,0);
                sr[3]=__builtin_shufflevector(sr[3],sr[3],1,0);
                si[3]=__builtin_shufflevector(si[3],si[3],1,0);
                // (3,0): c=slot, t=lane -> exchange slot-1 words across lanes
#pragma unroll
                for (int k = 0; k < 4; ++k) {
                    sr[k].y = __shfl_xor(sr[k].y, 1);
                    si[k].y = __shfl_xor(si[k].y, 1);
                }
            } else if (li == 1) {
                // (0,2): c=lane, t=reg bit0 -> lane1 swaps (0,1),(2,3)
                { v2 a=sr[0],b_=sr[1]; sr[0]=p?b_:a; sr[1]=p?a:b_;
                  v2 ai_=si[0],bi_=si[1]; si[0]=p?bi_:ai_; si[1]=p?ai_:bi_;
                  v2 c_=sr[2],d_=sr[3]; sr[2]=p?d_:c_; sr[3]=p?c_:d_;
                  v2 ci_=si[2],di_=si[3]; si[2]=p?di_:ci_; si[3]=p?ci_:di_; }
                // (1,3): c=reg bit1, t=slot -> slot-swap regs 2,3
                sr[2]=__builtin_shufflevector(sr[2],sr[2],1,0);
                si[2]=__builtin_shufflevector(si[2],si[2],1,0);
                sr[3]=__builtin_shufflevector(sr[3],sr[3],1,0);
                si[3]=__builtin_shufflevector(si[3],si[3],1,0);
                // (2,0): c=reg bit0, t=lane -> exchange regs 1,3 across lanes
#pragma unroll
                for (int k = 1; k < 4; k += 2) {
                    sr[k].x = __shfl_xor(sr[k].x, 1); sr[k].y = __shfl_xor(sr[k].y, 1);
                    si[k].x = __shfl_xor(si[k].x, 1); si[k].y = __shfl_xor(si[k].y, 1);
                }
                // (3,1): c=slot, t=reg bit1 -> slot-1 exchange in pairs (0,2),(1,3)
#pragma unroll
                for (int k = 0; k < 2; ++k) {
                    const int k2 = k | 2;
                    v2 Ar=sr[k], Br=sr[k2], Ai=si[k], Bi=si[k2];
                    sr[k]=__builtin_shufflevector(Ar,Br,0,3);
                    sr[k2]=__builtin_shufflevector(Br,Ar,0,3);
                    si[k]=__builtin_shufflevector(Ai,Bi,0,3);
                    si[k2]=__builtin_shufflevector(Bi,Ai,0,3);
                }
            } else {
                // (0,3): c=lane, t=slot -> lane1 slot-swaps all regs
#pragma unroll
                for (int k = 0; k < 4; ++k) {
                    const v2 wr=__builtin_shufflevector(sr[k],sr[k],1,0);
                    const v2 wi=__builtin_shufflevector(si[k],si[k],1,0);
                    sr[k] = p ? wr : sr[k];
                    si[k] = p ? wi : si[k];
                }
                // (1,0): c=reg bit1, t=lane -> exchange regs 2,3 across lanes
#pragma unroll
                for (int k = 2; k < 4; ++k) {
                    sr[k].x = __shfl_xor(sr[k].x, 1); sr[k].y = __shfl_xor(sr[k].y, 1);
                    si[k].x = __shfl_xor(si[k].x, 1); si[k].y = __shfl_xor(si[k].y, 1);
                }
                // (2,1): in-lane rename: swap regs 1,3
                { v2 t=sr[1]; sr[1]=sr[3]; sr[3]=t; t=si[1]; si[1]=si[3]; si[3]=t; }
                // (3,2): c=slot, t=reg bit0 -> slot-1 exchange in pairs (0,1),(2,3)
#pragma unroll
                for (int k = 0; k < 4; k += 2) {
                    const int k2 = k | 1;
                    v2 Ar=sr[k], Br=sr[k2], Ai=si[k], Bi=si[k2];
                    sr[k]=__builtin_shufflevector(Ar,Br,0,3);
                    sr[k2]=__builtin_shufflevector(Br,Ar,0,3);
                    si[k]=__builtin_shufflevector(Ai,Bi,0,3);
                    si[k2]=__builtin_shufflevector(Bi,Ai,0,3);
                }
            }
        }
    }

    // ---- <Z_q>: per-lane partials, then cross-lane add ----
    v2 a0 = {0.f,0.f}, a1 = {0.f,0.f}, a2 = {0.f,0.f}, a3 = {0.f,0.f};
    const v2 sgn3 = {1.f, -1.f};
#pragma unroll
    for (int k = 0; k < 4; ++k) {
        const v2 pk = sr[k]*sr[k] + si[k]*si[k];
        a0 += pk;                               // qubit0 sign handled by lane
        a1 += ((k >> 1) & 1) ? -pk : pk;        // qubit1 = reg bit1
        a2 += (k & 1) ? -pk : pk;               // qubit2 = reg bit0
        a3 += pk * sgn3;                        // qubit3 = slot
    }
    float e0 = a0.x + a0.y; e0 = p ? -e0 : e0;
    float e1 = a1.x + a1.y;
    float e2 = a2.x + a2.y;
    float e3 = a3.x + a3.y;
    e0 += __shfl_xor(e0, 1);
    e1 += __shfl_xor(e1, 1);
    e2 += __shfl_xor(e2, 1);
    e3 += __shfl_xor(e3, 1);
    if (p == 0) ((float4*)out)[b] = make_float4(e0, e1, e2, e3);
}

extern "C" void kernel_launch(void* const* d_in, const int* in_sizes, int n_in,
                              void* d_out, int out_size, void* d_ws, size_t ws_size,
                              hipStream_t stream) {
    const float* inputs = (const float*)d_in[0];   // [B,4] fp32
    const float* rot = (const float*)d_in[1];      // [6,4,3] fp32
    float* out = (float*)d_out;                    // [B,4] fp32
    const int batch = in_sizes[0] / NQ;
    const long long threads = 2LL * batch;
    const int grid = (int)((threads + BLOCK - 1) / BLOCK);
    vqc_kernel<<<grid, BLOCK, 0, stream>>>(inputs, rot, out, batch);
}